// Round 4
// baseline (110.367 us; speedup 1.0000x reference)
//
#include <hip/hip_runtime.h>
#include <math.h>

#define BOUNDF 10.0f
#define EPSF 1e-6f
#define MIN_SCALEF 1e-4f
#define DD 1024
#define KK 64
#define KP1 65

#define TD 32        // dims per block -> 128 B (full L2 line) per row per block
#define NCELL 256    // uniform search-seed cells per dim
#define TR 512       // rows per block -> grid = 32*16 = 512 = 2 blocks/CU exact
#define NT 512       // threads per block (64 rows x 8 dim-groups per pass)
#define ITER (TR / 64)
#define CPB (NCELL / (2.0f * BOUNDF))   // cells per unit z = 12.8

// native clang vector type: __builtin_nontemporal_* requires it
typedef float v4f __attribute__((ext_vector_type(4)));

// softplus robust to large |x|
__device__ __forceinline__ float softplus_f(float x) {
    return fmaxf(x, 0.0f) + __logf(1.0f + __expf(-fabsf(x)));
}

// ---------------------------------------------------------------------------
// Kernel 1: one block (1 wave) per dim.  Emits PACKED tables:
//   ivt (D,65) float4 {x0, y0, 1/w, h}   (entry 64 = {10,10,0,0} sentinel)
//   sl  (D,65) softplus slopes
//   grid(D,256) bytes: interval index containing each cell's start
//   scale (D)  softplus(log_scale)+MIN_SCALE
// ---------------------------------------------------------------------------
__global__ __launch_bounds__(64) void rqs_precompute(
    const float* __restrict__ raw_w, const float* __restrict__ raw_h,
    const float* __restrict__ raw_s, const float* __restrict__ log_scale,
    float4* __restrict__ ivt_g, float* __restrict__ sl_g,
    unsigned char* __restrict__ grid_g, float* __restrict__ scale_g)
{
    const int d = blockIdx.x;
    const int k = threadIdx.x;  // 0..63

    float ew = __expf(raw_w[d * KK + k]);
    float eh = __expf(raw_h[d * KK + k]);
    float sw = ew, sh = eh;
#pragma unroll
    for (int off = 1; off < 64; off <<= 1) {
        sw += __shfl_xor(sw, off, 64);
        sh += __shfl_xor(sh, off, 64);
    }
    float wk = ew * ((2.0f * BOUNDF) / sw);
    float hk = eh * ((2.0f * BOUNDF) / sh);
    float cw = wk, ch = hk;                    // inclusive prefix sums
#pragma unroll
    for (int off = 1; off < 64; off <<= 1) {
        float aw = __shfl_up(cw, off, 64);
        float ah = __shfl_up(ch, off, 64);
        if (k >= off) { cw += aw; ch += ah; }
    }
    // exclusive prefix = neighbor's inclusive prefix (bit-exact -> gap-free grid)
    float cwp = __shfl_up(cw, 1, 64); if (k == 0) cwp = 0.0f;
    float chp = __shfl_up(ch, 1, 64); if (k == 0) chp = 0.0f;
    float X  = -BOUNDF + cwp;
    float Yv = -BOUNDF + chp;
    float Xn = (k == 63) ? BOUNDF : (-BOUNDF + cw);
    float Yn = (k == 63) ? BOUNDF : (-BOUNDF + ch);
    ivt_g[d * KP1 + k] = make_float4(X, Yv, 1.0f / (Xn - X), Yn - Yv);
    sl_g[d * KP1 + k] = softplus_f(raw_s[d * KP1 + k]);
    if (k == 63) {
        ivt_g[d * KP1 + 64] = make_float4(BOUNDF, BOUNDF, 0.0f, 0.0f);
    }
    if (k == 0) {
        sl_g[d * KP1 + 64] = softplus_f(raw_s[d * KP1 + KK]);
        scale_g[d] = softplus_f(log_scale[d]) + MIN_SCALEF;
    }
    // grid: lane k owns cells whose start lies in [X_k, X_{k+1}).
    // c0(k) and c1(k-1) are ceil() of the SAME float -> exact partition.
    int c0 = (int)ceilf(cwp * CPB);
    int c1 = (k == 63) ? NCELL : (int)ceilf(cw * CPB);
    c1 = min(c1, NCELL);
    for (int c = c0; c < c1; ++c) grid_g[d * NCELL + c] = (unsigned char)k;
}

// ---------------------------------------------------------------------------
// Kernel 2: transform.  Block = 512 threads, tile = 32 dims x 512 rows.
// Thread t -> dims 4*(t&7).., row (t>>3): per row the block touches exactly
// one aligned 128-B line of u/out (no cross-XCD line splitting).
// Phase 1 = coalesced LDS copy of packed tables (~48.6 KB, L2-hit).
// Phase 2: O(1) grid seed + monotone fixup; one ds_read_b128 per element.
// LDS 48.6 KB -> 2 blocks/CU (16 waves/CU), grid 512 = 2 blocks/CU exact.
// ---------------------------------------------------------------------------
__global__ __launch_bounds__(NT, 2) void rqs_main(
    const float* __restrict__ u, const float* __restrict__ tau,
    const float* __restrict__ bias,
    const float4* __restrict__ ivt_g, const float* __restrict__ sl_g,
    const unsigned char* __restrict__ grid_g, const float* __restrict__ scale_g,
    float* __restrict__ out)
{
    __shared__ float4 livt[TD * KP1];          // 32.5 KB
    __shared__ float  lsl[TD * KP1];           //  8.1 KB
    __shared__ unsigned char lgr[TD * NCELL];  //  8.0 KB

    const int bx = blockIdx.x;
    const int dchunk = bx & (DD / TD - 1);     // fast idx: each XCD (bx%8) sees
    const int rchunk = bx >> 5;                //  only 4 dchunks -> tables L2-hot
    const int d0 = dchunk * TD;
    const int r0 = rchunk * TR;
    const int t = threadIdx.x;

    // ---- phase 1: stage packed tables (coalesced) ----
    for (int i = t; i < TD * KP1; i += NT) {
        livt[i] = ivt_g[d0 * KP1 + i];
        lsl[i]  = sl_g[d0 * KP1 + i];
    }
    {
        const unsigned int* gsrc = (const unsigned int*)(grid_g + d0 * NCELL);
        unsigned int* gdst = (unsigned int*)lgr;
        for (int i = t; i < TD * NCELL / 4; i += NT) gdst[i] = gsrc[i];
    }
    __syncthreads();

    // ---- phase 2: thread t -> dims 4*(t&7).., row r0 + (t>>3) ----
    const int g4 = (t & 7) * 4;
    const int rl = t >> 3;
    const int dg = d0 + g4;

    float sc[4], bi[4];
#pragma unroll
    for (int j = 0; j < 4; ++j) {
        sc[j] = scale_g[dg + j];
        bi[j] = bias[dg + j];
    }

    int b = r0 + rl;
    v4f uu = __builtin_nontemporal_load((const v4f*)(u + (size_t)b * DD + dg));
    float tb = tau[b];

#pragma unroll 1
    for (int it = 0; it < ITER; ++it) {
        const v4f ucur = uu;
        const float tcur = tb;
        const int bcur = b;
        if (it + 1 < ITER) {                   // software pipeline next load
            b += 64;
            uu = __builtin_nontemporal_load((const v4f*)(u + (size_t)b * DD + dg));
            tb = tau[b];
        }
        float ua[4] = {ucur.x, ucur.y, ucur.z, ucur.w};
        float res[4];
#pragma unroll
        for (int j = 0; j < 4; ++j) {
            float uv = fminf(fmaxf(ua[j], EPSF), 1.0f - EPSF);
            float z = __logf(uv * __builtin_amdgcn_rcpf(1.0f - uv));
            // cap just below +10 so fixup terminates at lo=63 (sentinel x=10)
            float zc = fminf(fmaxf(z, -BOUNDF), 9.9999990f);
            const int ib = (g4 + j) * KP1;
            int cell = (int)fmaf(zc, CPB, 0.5f * NCELL);
            int lo = (int)lgr[(g4 + j) * NCELL + cell];   // seed <= true bin
            float nx = livt[ib + lo + 1].x;
            bool adv = (nx <= zc);
            while (__any(adv)) {               // avg ~1 whole-wave iteration
                lo += adv;
                nx = livt[ib + lo + 1].x;
                adv = adv && (nx <= zc);
            }
            float4 iv = livt[ib + lo];         // one ds_read_b128
            float dd0 = lsl[ib + lo];          // ds_read2_b32 pair
            float dd1 = lsl[ib + lo + 1];
            float th  = (zc - iv.x) * iv.z;
            float s   = iv.w * iv.z;           // h/w
            float t1m = th * (1.0f - th);
            float den = fmaf(fmaf(-2.0f, s, dd0 + dd1), t1m, s);
            float num = iv.w * fmaf(s * th, th, dd0 * t1m);
            float y = fmaf(num, __builtin_amdgcn_rcpf(den), iv.y);
            y = (fabsf(z) < BOUNDF) ? y : z;   // passthrough outside
            res[j] = tcur * fmaf(y, sc[j], bi[j]);
        }
        v4f ro;
        ro.x = res[0]; ro.y = res[1]; ro.z = res[2]; ro.w = res[3];
        __builtin_nontemporal_store(ro, (v4f*)(out + (size_t)bcur * DD + dg));
    }
}

// ---------------------------------------------------------------------------
extern "C" void kernel_launch(void* const* d_in, const int* in_sizes, int n_in,
                              void* d_out, int out_size, void* d_ws, size_t ws_size,
                              hipStream_t stream)
{
    const float* u         = (const float*)d_in[0];
    const float* tau       = (const float*)d_in[1];
    const float* log_scale = (const float*)d_in[2];
    const float* bias      = (const float*)d_in[3];
    const float* raw_w     = (const float*)d_in[4];
    const float* raw_h     = (const float*)d_in[5];
    const float* raw_s     = (const float*)d_in[6];
    float* out = (float*)d_out;

    // workspace layout (needs ~1.6 MB)
    float* ws = (float*)d_ws;
    float4* ivt = (float4*)ws;                               // D*65 float4
    float* sl = ws + (size_t)DD * KP1 * 4;                   // D*65 floats
    unsigned char* grid = (unsigned char*)(sl + DD * KP1);   // D*256 bytes
    float* scale = (float*)(grid + (size_t)DD * NCELL);      // D floats

    const int B = in_sizes[0] / DD;                          // 8192

    rqs_precompute<<<DD, 64, 0, stream>>>(raw_w, raw_h, raw_s, log_scale,
                                          ivt, sl, grid, scale);
    rqs_main<<<(DD / TD) * (B / TR), NT, 0, stream>>>(
        u, tau, bias, ivt, sl, grid, scale, out);
}